// Round 1
// baseline (542.840 us; speedup 1.0000x reference)
//
#include <hip/hip_runtime.h>
#include <hip/hip_bf16.h>

#define CHW4 16384   // one bg-group in float4 (16 ch * 64 * 64 / 4)
#define STR  84      // staging row stride in floats (72 used + pad, bank-spread)

__device__ __forceinline__ float wred(float v){
#pragma unroll
  for (int o = 32; o; o >>= 1) v += __shfl_xor(v, o, 64);
  return v;
}
__device__ __forceinline__ float wred16(float v){
#pragma unroll
  for (int o = 8; o; o >>= 1) v += __shfl_xor(v, o, 64);
  return v;
}
__device__ __forceinline__ float bf2f(unsigned short u){
  return __uint_as_float(((unsigned)u) << 16);
}
__device__ __forceinline__ unsigned short f2b(float f){
  union { __hip_bfloat16 h; unsigned short u; } cv;
  cv.h = __float2bfloat16(f);
  return cv.u;
}

// One block per bg-group. Phases:
//  conv3x3 (E3=exp(relu(x3)) bf16 -> LDS, V3/Z3 stripe partials -> LDS)
//  pass0 row/col pooling -> a_h/a_w; passA mu/var + chsum; passB Z2 (+exp(x2)
//  kept bf16 in regs); passC t from regs+LDS; passD out = x*softmax(t).
__global__ __launch_bounds__(1024, 4) void ema_fused(const float* __restrict__ x,
    const float* __restrict__ w1, const float* __restrict__ b1,
    const float* __restrict__ wh, const float* __restrict__ bh,
    const float* __restrict__ ww, const float* __restrict__ bw,
    const float* __restrict__ w3, const float* __restrict__ b3,
    const float* __restrict__ gnw, const float* __restrict__ gnb,
    float* __restrict__ out)
{
  // LDS budget: 131072 + 26880 + 1024 + 2048 + 128 + 8 + 320 + 4 = 161484 B
  __shared__ __align__(16) unsigned short E3s[16*4096];  // exp(relu(conv3)) bf16, [co][h*64+w]
  __shared__ __align__(16) float uni[6720];              // conv staging  |  rs/cs/ym/ahs/aws
  __shared__ float v3p[128], z3p[128];                   // [stripe 0..7][co 0..15]
  __shared__ float chpart[256], zpart[256];
  __shared__ float red1[16], red2[16];
  __shared__ float murs[2];
  __shared__ float sc_s[16], of_s[16], v2_s[16], p2s[16], p3s[16];
  __shared__ float invS_s;

  const int tid = threadIdx.x;
  const int bg  = blockIdx.x;
  const float4* x4 = (const float4*)x + (size_t)bg * CHW4;
  float4* o4 = (float4*)out + (size_t)bg * CHW4;

  const int lane = tid & 63;
  const int unit = __builtin_amdgcn_readfirstlane(tid >> 8);       // 0..3, wave-uniform
  const int ut   = tid & 255;                                      // thread-in-unit
  const int cog  = __builtin_amdgcn_readfirstlane((tid & 255) >> 6); // wave-in-unit 0..3
  const int co0  = cog * 4;
  const int cr   = lane >> 3;          // conv output row within stripe
  const int w0   = (lane & 7) * 8;     // 8 consecutive output cols
  float* in_u = &uni[unit * 1680];     // 2ci x 10 rows x STR floats

  // round-invariant staging map: idx = c2*180 + rr*18 + q, idx in [0,360)
  const int q0  = ut % 18, rr0 = (ut / 18) % 10, c20 = ut / 180;
  const int ut1 = ut + 256;
  const int q1  = ut1 % 18, rr1 = (ut1 / 18) % 10, c21 = ut1 / 180;
  const bool have1 = (ut < 104);

  // ================= conv phase =================
  float acc[4][8];
#pragma unroll
  for (int i = 0; i < 4; ++i)
#pragma unroll
    for (int px = 0; px < 8; ++px) acc[i][px] = 0.f;

  float4 pa, pb;
  {  // prefetch round 0 (stripe = unit*2, ci chunk 0)
    int hb = unit*16 - 1;
    pa = make_float4(0.f,0.f,0.f,0.f); pb = make_float4(0.f,0.f,0.f,0.f);
    int hh0 = hb + rr0;
    if (q0 >= 1 && q0 <= 16 && (unsigned)hh0 < 64u)
      pa = x4[c20*1024 + hh0*16 + (q0-1)];
    if (have1){
      int hh1 = hb + rr1;
      if (q1 >= 1 && q1 <= 16 && (unsigned)hh1 < 64u)
        pb = x4[c21*1024 + hh1*16 + (q1-1)];
    }
  }

#pragma unroll 1
  for (int round = 0; round < 16; ++round){
    __syncthreads();                       // prev round's LDS reads done
    *(float4*)&in_u[(c20*10 + rr0)*STR + q0*4] = pa;
    if (have1) *(float4*)&in_u[(c21*10 + rr1)*STR + q1*4] = pb;
    __syncthreads();                       // staged data visible
    if (round < 15){                       // issue next round's loads early (hide under FMA)
      int rn = round + 1;
      int sg = unit*2 + (rn >> 3);
      int cb = (rn & 7) * 2;
      int hb = sg*8 - 1;
      pa = make_float4(0.f,0.f,0.f,0.f); pb = make_float4(0.f,0.f,0.f,0.f);
      int hh0 = hb + rr0;
      if (q0 >= 1 && q0 <= 16 && (unsigned)hh0 < 64u)
        pa = x4[(cb + c20)*1024 + hh0*16 + (q0-1)];
      if (have1){
        int hh1 = hb + rr1;
        if (q1 >= 1 && q1 <= 16 && (unsigned)hh1 < 64u)
          pb = x4[(cb + c21)*1024 + hh1*16 + (q1-1)];
      }
    }
    const int ch2 = (round & 7) * 2;
#pragma unroll
    for (int c2 = 0; c2 < 2; ++c2){
      const int ci = ch2 + c2;
      float wgt[4][9];
#pragma unroll
      for (int i = 0; i < 4; ++i)
#pragma unroll
        for (int t = 0; t < 9; ++t)
          wgt[i][t] = w3[((co0+i)*16 + ci)*9 + t];   // wave-uniform -> scalar loads
#pragma unroll
      for (int dy = 0; dy < 3; ++dy){
        const float* rowp = &in_u[(c2*10 + cr + dy)*STR + w0];
        float4 A0  = *(const float4*)(rowp);
        float4 A1  = *(const float4*)(rowp+4);
        float4 A2v = *(const float4*)(rowp+8);
        float4 A3v = *(const float4*)(rowp+12);
        float v[16] = {A0.x,A0.y,A0.z,A0.w, A1.x,A1.y,A1.z,A1.w,
                       A2v.x,A2v.y,A2v.z,A2v.w, A3v.x,A3v.y,A3v.z,A3v.w};
#pragma unroll
        for (int dx = 0; dx < 3; ++dx)
#pragma unroll
          for (int px = 0; px < 8; ++px){
            float iv = v[px + dx + 3];
#pragma unroll
            for (int i = 0; i < 4; ++i)
              acc[i][px] = fmaf(wgt[i][dy*3+dx], iv, acc[i][px]);
          }
      }
    }
    if ((round & 7) == 7){
      // stripe epilogue: relu/exp -> E3s (bf16), V3/Z3 stripe partials
      const int sg = unit*2 + (round >> 3);
      const int hh = sg*8 + cr;
#pragma unroll
      for (int i = 0; i < 4; ++i){
        float bias = b3[co0+i];
        union { unsigned short hb16[8]; uint4 u; } pk;
        float v3acc = 0.f, z3acc = 0.f;
#pragma unroll
        for (int px = 0; px < 8; ++px){
          float val = fmaxf(acc[i][px] + bias, 0.f);
          float e = __expf(val);
          v3acc += val; z3acc += e;
          pk.hb16[px] = f2b(e);
          acc[i][px] = 0.f;                 // reset for next stripe
        }
        *(uint4*)&E3s[(co0+i)*4096 + hh*64 + w0] = pk.u;
        float rv = wred(v3acc);
        float rz = wred(z3acc);
        if (lane == 0){
          v3p[sg*16 + co0 + i] = rv;
          z3p[sg*16 + co0 + i] = rz;
        }
      }
    }
  }

  // ================= pooled-attention + stats =================
  float* rs  = uni;          // [1024] rowsum
  float* cs  = uni + 1024;   // [1024] colsum
  float* ym  = uni + 2048;   // [2048]
  float* ahs = uni + 4096;   // [1024]
  float* aws = uni + 5120;   // [1024]
  const int h   = tid >> 4;
  const int w4i = tid & 15;
  const int wv  = tid >> 6;

  __syncthreads();           // conv done: staging region reusable
  cs[tid] = 0.f;
  __syncthreads();
#pragma unroll 8
  for (int k = 0; k < 16; ++k){
    float4 v = x4[k*1024 + tid];
    float srow = v.x + v.y + v.z + v.w;
    srow = wred16(srow);
    if ((tid & 15) == 0) rs[k*64 + h] = srow;
    v.x += __shfl_xor(v.x, 16); v.x += __shfl_xor(v.x, 32);
    v.y += __shfl_xor(v.y, 16); v.y += __shfl_xor(v.y, 32);
    v.z += __shfl_xor(v.z, 16); v.z += __shfl_xor(v.z, 32);
    v.w += __shfl_xor(v.w, 16); v.w += __shfl_xor(v.w, 32);
    if (lane < 16){
      atomicAdd(&cs[k*64 + lane*4 + 0], v.x);
      atomicAdd(&cs[k*64 + lane*4 + 1], v.y);
      atomicAdd(&cs[k*64 + lane*4 + 2], v.z);
      atomicAdd(&cs[k*64 + lane*4 + 3], v.w);
    }
  }
  __syncthreads();
  for (int ol = tid; ol < 2048; ol += 1024){
    int o = ol >> 7, l = ol & 127;
    float a = b1[o];
#pragma unroll
    for (int i = 0; i < 16; ++i){
      float mv = (l < 64 ? rs[i*64 + l] : cs[i*64 + (l-64)]) * (1.f/64.f);
      a = fmaf(w1[o*16 + i], mv, a);
    }
    ym[o*128 + l] = fmaxf(a, 0.f);
  }
  __syncthreads();
  for (int ol = tid; ol < 2048; ol += 1024){
    int q = ol >> 10;
    int o = (ol >> 6) & 15;
    int p = ol & 63;
    const float* Wm = q ? ww : wh;
    float a = q ? bw[o] : bh[o];
#pragma unroll
    for (int i = 0; i < 16; ++i)
      a = fmaf(Wm[o*16 + i], ym[i*128 + q*64 + p], a);
    float sgm = 1.f / (1.f + __expf(-a));
    (q ? aws : ahs)[o*64 + p] = sgm;
  }
  __syncthreads();

  // ---- pass A: mu/var + per-channel sums ----
  const float4* aws4 = (const float4*)aws;
  float s1 = 0.f, s2 = 0.f;
#pragma unroll 8
  for (int k = 0; k < 16; ++k){
    float4 v = x4[k*1024 + tid];
    float ah = ahs[k*64 + h];
    float4 aw = aws4[k*16 + w4i];
    float4 x1;
    x1.x = v.x * ah * aw.x;
    x1.y = v.y * ah * aw.y;
    x1.z = v.z * ah * aw.z;
    x1.w = v.w * ah * aw.w;
    float csum = x1.x + x1.y + x1.z + x1.w;
    s1 += csum;
    s2 = fmaf(x1.x, x1.x, s2); s2 = fmaf(x1.y, x1.y, s2);
    s2 = fmaf(x1.z, x1.z, s2); s2 = fmaf(x1.w, x1.w, s2);
    float cw = wred(csum);
    if (lane == 0) chpart[k*16 + wv] = cw;
  }
  float r1 = wred(s1), r2 = wred(s2);
  if (lane == 0){ red1[wv] = r1; red2[wv] = r2; }
  __syncthreads();
  if (tid == 0){
    float S = 0.f, SS = 0.f;
#pragma unroll
    for (int i = 0; i < 16; ++i){ S += red1[i]; SS += red2[i]; }
    float mu  = S * (1.f/65536.f);
    float var = SS * (1.f/65536.f) - mu*mu;
    murs[0] = mu; murs[1] = rsqrtf(var + 1e-5f);
  }
  __syncthreads();
  if (tid < 16){
    float ch = 0.f;
#pragma unroll
    for (int m = 0; m < 16; ++m) ch += chpart[tid*16 + m];
    float mu = murs[0], rstd = murs[1];
    float g = gnw[tid], b = gnb[tid];
    float sc = rstd * g;
    sc_s[tid] = sc; of_s[tid] = b - mu*sc;
    v2_s[tid] = (ch * (1.f/4096.f) - mu) * sc + b;   // V2
  }
  __syncthreads();

  // ---- pass B: Z2 per channel; keep exp(x2) bf16-packed in regs ----
  unsigned e2a[16], e2b[16];
#pragma unroll
  for (int k = 0; k < 16; ++k){
    float4 v = x4[k*1024 + tid];
    float ah = ahs[k*64 + h];
    float4 aw = aws4[k*16 + w4i];
    float sc = sc_s[k], of = of_s[k];
    float ex = __expf(fmaf(v.x * ah * aw.x, sc, of));
    float ey = __expf(fmaf(v.y * ah * aw.y, sc, of));
    float ez = __expf(fmaf(v.z * ah * aw.z, sc, of));
    float ew = __expf(fmaf(v.w * ah * aw.w, sc, of));
    float z = ex + ey + ez + ew;
    e2a[k] = (unsigned)f2b(ex) | ((unsigned)f2b(ey) << 16);
    e2b[k] = (unsigned)f2b(ez) | ((unsigned)f2b(ew) << 16);
    float zw = wred(z);
    if (lane == 0) zpart[k*16 + wv] = zw;
  }
  __syncthreads();
  if (tid < 16){
    float z2 = 0.f;
#pragma unroll
    for (int m = 0; m < 16; ++m) z2 += zpart[tid*16 + m];
    float v3 = 0.f, z3 = 0.f;
#pragma unroll
    for (int ss = 0; ss < 8; ++ss){
      v3 += v3p[ss*16 + tid];
      z3 += z3p[ss*16 + tid];
    }
    p2s[tid] = v3 * (1.f/4096.f) / z2;   // multiplies exp(x2):  V3 * A2
    p3s[tid] = v2_s[tid] / z3;           // multiplies exp(x3):  V2 * A3
  }
  __syncthreads();

  // ---- pass C: t from register exp(x2) + LDS E3 (no x re-read) ----
  float4 tacc = make_float4(0.f,0.f,0.f,0.f);
#pragma unroll
  for (int k = 0; k < 16; ++k){
    ushort4 eu = *(const ushort4*)&E3s[k*4096 + tid*4];
    float p2 = p2s[k], p3 = p3s[k];
    tacc.x += bf2f((unsigned short)(e2a[k] & 0xffffu))*p2 + bf2f(eu.x)*p3;
    tacc.y += bf2f((unsigned short)(e2a[k] >> 16))   *p2 + bf2f(eu.y)*p3;
    tacc.z += bf2f((unsigned short)(e2b[k] & 0xffffu))*p2 + bf2f(eu.z)*p3;
    tacc.w += bf2f((unsigned short)(e2b[k] >> 16))   *p2 + bf2f(eu.w)*p3;
  }
  float4 e;
  e.x = __expf(tacc.x); e.y = __expf(tacc.y);
  e.z = __expf(tacc.z); e.w = __expf(tacc.w);
  float es = e.x + e.y + e.z + e.w;
  float rr = wred(es);
  if (lane == 0) red1[wv] = rr;
  __syncthreads();
  if (tid == 0){
    float S = 0.f;
#pragma unroll
    for (int i = 0; i < 16; ++i) S += red1[i];
    invS_s = 1.f / S;
  }
  __syncthreads();
  float iS = invS_s;
  float4 ei = make_float4(e.x*iS, e.y*iS, e.z*iS, e.w*iS);

  // ---- pass D: out = x * s ----
#pragma unroll 8
  for (int k = 0; k < 16; ++k){
    float4 v = x4[k*1024 + tid];
    float4 ov;
    ov.x = v.x * ei.x; ov.y = v.y * ei.y;
    ov.z = v.z * ei.z; ov.w = v.w * ei.w;
    o4[k*1024 + tid] = ov;
  }
}

extern "C" void kernel_launch(void* const* d_in, const int* in_sizes, int n_in,
                              void* d_out, int out_size, void* d_ws, size_t ws_size,
                              hipStream_t stream)
{
  const float* x   = (const float*)d_in[0];
  const float* w1  = (const float*)d_in[1];
  const float* b1  = (const float*)d_in[2];
  const float* wh  = (const float*)d_in[3];
  const float* bh  = (const float*)d_in[4];
  const float* ww  = (const float*)d_in[5];
  const float* bw  = (const float*)d_in[6];
  const float* w3  = (const float*)d_in[7];
  const float* b3  = (const float*)d_in[8];
  const float* gnw = (const float*)d_in[9];
  const float* gnb = (const float*)d_in[10];
  float* out = (float*)d_out;
  (void)d_ws; (void)ws_size; (void)n_in; (void)in_sizes; (void)out_size;

  ema_fused<<<dim3(512), 1024, 0, stream>>>(x, w1, b1, wh, bh, ww, bw,
                                            w3, b3, gnw, gnb, out);
}